// Round 5
// baseline (233.387 us; speedup 1.0000x reference)
//
#include <hip/hip_runtime.h>

// YOLO layer: (64, 3*85, 44, 44) -> (64, 3*44*44, 85), fp32.
// R4 post-mortem: bank conflicts 4.86M->0.99M as predicted, but dur 79->85 us
// => conflicts were not the critical path. All pipes idle (HBM 28%, VALU 22%,
// Occ 62%) = exposed-latency convoy: one-shot blocks pay ~900cyc load latency
// + a block-wide barrier per 64-spatial tile.
// R5: barrier-free wave-private streaming pipeline.
//  - wave w owns spatial rows [16w,16w+16) of each tile: loads (16x64B
//    segments/instr), transforms, writes its OWN 16x85 LDS region, reads it
//    back contiguous (ds_read_b128), NT-stores. Producer==consumer==same wave
//    => NO __syncthreads anywhere; ordering is compiler lgkmcnt.
//  - persistent blocks: 1488 blocks x 4 consecutive tiles; issue tile k+1's
//    loads BEFORE transforming tile k => HBM latency hides under prev tile's
//    transform+flush (counted vmcnt, stores stay outstanding).
//  - keep NT stores (R3/R4: FETCH 61.8MB < 126MB input = L3-resident input)
//    and bijective XCD chunk swizzle (1488 % 8 == 0).

#define BSZ      64
#define NA       3
#define NC       80
#define GRID     44
#define SPATIAL  (GRID * GRID)        // 1936
#define CH       (5 + NC)             // 85
#define TILE     64
#define TPB      31                   // tiles per (b,a) slab
#define NTL      (BSZ * NA * TPB)     // 5952 tiles
#define NT       4                    // tiles per block
#define NBLK     (NTL / NT)           // 1488
#define NXCD     8
#define CHUNKB   (NBLK / NXCD)        // 186
#define STRIDE_F 8.0f                 // 352/44; cancels /STRIDE in scaled anchors

typedef float vfloat4 __attribute__((ext_vector_type(4)));

__device__ __forceinline__ float sigf(float x) {
    return 1.0f / (1.0f + __expf(-x));
}

struct TileCtx { int s0, valid, ba; float aw, ah; };

__device__ __forceinline__ TileCtx tctx(int T) {
    TileCtx tc;
    int t   = T % TPB;                 // magic-mul
    tc.ba   = T / TPB;
    tc.s0   = t * TILE;
    tc.valid = min(TILE, SPATIAL - tc.s0);   // 64, or 16 on last tile of slab
    int a = tc.ba % NA;
    tc.aw = (a == 0) ? 10.0f : (a == 1) ? 16.0f : 33.0f;
    tc.ah = (a == 0) ? 13.0f : (a == 1) ? 30.0f : 23.0f;
    return tc;
}

// Issue this wave's 6 float4 loads for one tile (predicated, stay in flight).
__device__ __forceinline__ void issue_loads(const float* __restrict__ in,
                                            const TileCtx& tc, int w, int l,
                                            float4 (&v)[6]) {
    const bool wact = (16 * w < tc.valid);
    const float* ib = in + (size_t)tc.ba * CH * SPATIAL + tc.s0 + 16 * w;
    #pragma unroll
    for (int i = 0; i < 6; ++i) {
        int p = i * 64 + l;           // pair index: c = p>>2, quad = p&3
        int c = p >> 2, ql = p & 3;
        if (wact && p < 340)          // 85*4 = 340 pairs; i<5 always active
            v[i] = *(const float4*)(ib + (size_t)c * SPATIAL + 4 * ql);
    }
}

// Transform + transpose-write into this wave's private 16x85 LDS region.
__device__ __forceinline__ void transform(const TileCtx& tc, int w, int l,
                                          const float4 (&v)[6],
                                          float* __restrict__ wlds) {
    const bool wact = (16 * w < tc.valid);
    #pragma unroll
    for (int i = 0; i < 6; ++i) {
        int p = i * 64 + l;
        int c = p >> 2, ql = p & 3;
        if (!wact || p >= 340) continue;
        float r[4] = {v[i].x, v[i].y, v[i].z, v[i].w};
        #pragma unroll
        for (int j = 0; j < 4; ++j) {
            int   sl = ql * 4 + j;                    // local row (0..15)
            int   gs = tc.s0 + 16 * w + 4 * ql + j;   // global spatial
            float x  = r[j];
            float o;
            if (c == 0)      o = (sigf(x) + (float)(gs % GRID)) * STRIDE_F;
            else if (c == 1) o = (sigf(x) + (float)(gs / GRID)) * STRIDE_F;
            else if (c == 2) o = __expf(x) * tc.aw;
            else if (c == 3) o = __expf(x) * tc.ah;
            else             o = sigf(x);             // conf + 80 classes
            wlds[sl * CH + c] = o;                    // <=3-way bank alias
        }
    }
}

// Contiguous ds_read_b128 of the wave's region + NT float4 stores.
__device__ __forceinline__ void flush(float* __restrict__ out,
                                      const TileCtx& tc, int w, int l,
                                      const float* __restrict__ wlds) {
    if (16 * w >= tc.valid) return;
    const size_t ob = ((size_t)tc.ba * SPATIAL + tc.s0 + 16 * w) * (size_t)CH;
    #pragma unroll
    for (int i = 0; i < 6; ++i) {
        int k = i * 256 + 4 * l;      // 16*85 = 1360 floats; i=5: l<20
        if (k < 16 * CH) {
            vfloat4 x = *(const vfloat4*)(wlds + k);
            __builtin_nontemporal_store(x, (vfloat4*)(out + ob + k));
        }
    }
}

__global__ __launch_bounds__(256, 7)
void yolo_kernel(const float* __restrict__ in, float* __restrict__ out) {
    __shared__ float lds[4 * 16 * CH];    // 4 wave-private 16x85 regions, 21760 B

    const int bid0 = blockIdx.x;
    const int bid  = (bid0 % NXCD) * CHUNKB + bid0 / NXCD;   // XCD-chunked
    const int tid  = threadIdx.x;
    const int w    = tid >> 6, l = tid & 63;
    float* wlds = lds + w * 16 * CH;

    const int T0 = bid * NT;
    float4 vA[6], vB[6];

    TileCtx tc = tctx(T0);
    issue_loads(in, tc, w, l, vA);

    #pragma unroll
    for (int k = 0; k < NT; ++k) {
        TileCtx tn;
        if (k + 1 < NT) {                      // prefetch next tile's loads
            tn = tctx(T0 + k + 1);
            issue_loads(in, tn, w, l, vB);
        }
        transform(tc, w, l, vA, wlds);         // waits vmcnt(6) for vA only
        flush(out, tc, w, l, wlds);            // lgkmcnt-ordered, no barrier
        if (k + 1 < NT) {
            tc = tn;
            #pragma unroll
            for (int i = 0; i < 6; ++i) vA[i] = vB[i];   // renamed by unroll
        }
    }
}

extern "C" void kernel_launch(void* const* d_in, const int* in_sizes, int n_in,
                              void* d_out, int out_size, void* d_ws, size_t ws_size,
                              hipStream_t stream) {
    const float* in = (const float*)d_in[0];
    float* out = (float*)d_out;
    yolo_kernel<<<NBLK, 256, 0, stream>>>(in, out);
}

// Round 6
// 228.250 us; speedup vs baseline: 1.0225x; 1.0225x over previous
//
#include <hip/hip_runtime.h>

// YOLO layer: (64, 3*85, 44, 44) -> (64, 3*44*44, 85), fp32.
// R3/R4/R5 post-mortem: three different structures (block convoy stride-89,
// packed LDS, barrier-free persistent pipeline) all land at 79-87 us kernel
// with EVERY on-chip pipe idle (VALU 22-28%, HBM 28-30%, conflicts ~0,
// ~1K VMEM instrs/CU over 208K cycles). Limiter is the shared memory system,
// but copy (m13) proves 6.29 TB/s for the same 1:1 R:W mix -> our pattern
// deviates only in (a) 256B-granule reads, (b) nt stores. NT was adopted on
// an L3-thrash theory whose evidence (FETCH=input/2) is better explained by
// the harness's out-buffer re-poison memset. NT never A/B'd -> R6 drops it.
// One change vs R4: normal write-allocate vfloat4 stores (L2 write-back
// aggregation). R5 lesson kept: >=256B read granules (16 lanes/channel).

#define BSZ      64
#define NA       3
#define NC       80
#define GRID     44
#define SPATIAL  (GRID * GRID)       // 1936
#define CH       (5 + NC)            // 85
#define TILE     64
#define TILES_PER_BA ((SPATIAL + TILE - 1) / TILE)   // 31 (last tile: 16 valid)
#define NF       (CH * (TILE / 4))   // 1360 float4 loads per block
#define NITER    ((NF + 255) / 256)  // 6
#define STRIDE_F 8.0f                // 352 / 44; cancels /STRIDE in scaled anchors
#define NXCD     8
#define NWG      (BSZ * NA * TILES_PER_BA)   // 5952 (divisible by 8)
#define CHUNK    (NWG / NXCD)                // 744

typedef float vfloat4 __attribute__((ext_vector_type(4)));

__device__ __forceinline__ float sigf(float x) {
    return 1.0f / (1.0f + __expf(-x));
}

__global__ __launch_bounds__(256, 4)
void yolo_kernel(const float* __restrict__ in, float* __restrict__ out) {
    __shared__ float tile[TILE * CH];     // packed [s][c], 21760 B -> 7 blocks/CU

    // XCD-chunked swizzle (bijective since NWG%8==0).
    const int bid0 = blockIdx.x;
    const int bid  = (bid0 % NXCD) * CHUNK + bid0 / NXCD;

    const int t   = bid % TILES_PER_BA;
    const int ba  = bid / TILES_PER_BA;   // b*NA + a
    const int a   = ba % NA;

    const int s0    = t * TILE;
    const int valid = min(TILE, SPATIAL - s0);   // 64 or 16; always mult of 4

    const float aw = (a == 0) ? 10.0f : (a == 1) ? 16.0f : 33.0f;
    const float ah = (a == 0) ? 13.0f : (a == 1) ? 30.0f : 23.0f;

    const int tid = threadIdx.x;
    const float* inbase = in + (size_t)ba * CH * SPATIAL + s0;

    // ---- phase 1a: issue ALL global loads first (bytes in flight) ----
    // lane->(c, quad): 16 lanes per channel -> 256B contiguous per channel row.
    float4 v[NITER];
    #pragma unroll
    for (int i = 0; i < NITER; ++i) {
        int f = tid + i * 256;            // f -> (channel c, spatial quad q)
        int c = f >> 4, q = f & 15;
        if (f < NF && q * 4 < valid)
            v[i] = *(const float4*)(inbase + (size_t)c * SPATIAL + q * 4);
    }

    // ---- phase 1b: transform + LDS transpose write (packed [s][c]) ----
    #pragma unroll
    for (int i = 0; i < NITER; ++i) {
        int f = tid + i * 256;
        int c = f >> 4, q = f & 15;
        if (f >= NF || q * 4 >= valid) continue;
        float r[4] = {v[i].x, v[i].y, v[i].z, v[i].w};
        #pragma unroll
        for (int j = 0; j < 4; ++j) {
            int   sl = q * 4 + j;         // local spatial
            int   gs = s0 + sl;           // global spatial
            float x  = r[j];
            float o;
            if (c == 0)      o = (sigf(x) + (float)(gs % GRID)) * STRIDE_F;
            else if (c == 1) o = (sigf(x) + (float)(gs / GRID)) * STRIDE_F;
            else if (c == 2) o = __expf(x) * aw;
            else if (c == 3) o = __expf(x) * ah;
            else             o = sigf(x);  // conf + 80 classes
            tile[sl * CH + c] = o;        // 2-way max bank aliasing (free)
        }
    }
    __syncthreads();

    // ---- phase 2: contiguous ds_read_b128 + normal float4 store ----
    // LDS is the exact output image of this block: copy valid*CH floats.
    const size_t obase = ((size_t)ba * SPATIAL + s0) * CH;  // 16B-aligned
    const int total = valid * CH;         // 5440 or 1360, both mult of 4
    for (int k4 = tid * 4; k4 < total; k4 += 1024) {
        vfloat4 w = *(const vfloat4*)(tile + k4);   // lane-contiguous: no conflicts
        *(vfloat4*)(out + obase + k4) = w;          // write-allocate, L2 aggregated
    }
}

extern "C" void kernel_launch(void* const* d_in, const int* in_sizes, int n_in,
                              void* d_out, int out_size, void* d_ws, size_t ws_size,
                              hipStream_t stream) {
    const float* in = (const float*)d_in[0];
    float* out = (float*)d_out;
    yolo_kernel<<<NWG, 256, 0, stream>>>(in, out);
}